// Round 6
// baseline (63.837 us; speedup 1.0000x reference)
//
#include <hip/hip_runtime.h>

// LIF neuron scan: x [64, 1024, 512] f32 -> spikes [64, 1024, 512] f32 (0/1)
// m = 0.95*m + x[t]; s = (m > 0.5); m = s ? 0 : m
//
// 32768 sequential chains -> only 512 compute waves (2/CU): both the register
// ping-pong (46.9us) and LDS dwordx4 (49.4us) versions plateau at ~5.3 TB/s
// demand BW. Per-wave MLP arithmetic clears the latency-BW product, so the
// wall is the THIN REQUEST STREAM: 2 waves/CU can't drive HBM the way
// fillBuffer's trivially-parallel stream does (7.0 TB/s at 3 waves/CU).
//
// Fix: decouple reads from the sequential chains. 1536 extra pure-prefetch
// blocks stream all of x (coalesced 1KB/instr dwordx4), quadrupling the
// read-issuing wave count and pulling x into L3 ahead of consumption
// (x = 128MB < 256MB L3). Compute blocks then mostly L3-hit. Prefetchers
// cannot affect results -> exactness preserved. Keep-alive asm prevents DCE
// of the prefetch loads (guide rule #17).
//
// Compute path unchanged from the 46.9us version: CHUNK=64 static ping-pong,
// non-fused mul/add (np ref rounds separately; the 0/1 threshold makes ulp
// differences avalanche), nt dword stores.

#define BATCH 64
#define SEQ   1024
#define FEAT  512
#define CHUNK 64
#define NCOMPUTE  512                       // compute blocks (1 wave each)
#define NPREFETCH 1536                      // prefetch blocks (1 wave each)
#define UNITS (BATCH * SEQ * FEAT * 4 / 1024)   // 131072 x 1KB units

typedef float f32x4 __attribute__((ext_vector_type(4)));

#define LOAD_CHUNK(buf, t0)                                              \
    {                                                                    \
        const float* __restrict__ xn = xp + (size_t)(t0) * FEAT;         \
        _Pragma("unroll")                                                \
        for (int u = 0; u < CHUNK; ++u) buf[u] = xn[(size_t)u * FEAT];   \
    }

#define COMPUTE_CHUNK(buf, t0)                                           \
    {                                                                    \
        float* __restrict__ on = op + (size_t)(t0) * FEAT;               \
        _Pragma("unroll")                                                \
        for (int u = 0; u < CHUNK; ++u) {                                \
            m = __fadd_rn(__fmul_rn(0.95f, m), buf[u]);                  \
            const bool fired = (m > 0.5f);                               \
            __builtin_nontemporal_store(fired ? 1.0f : 0.0f,             \
                                        &on[(size_t)u * FEAT]);          \
            m = fired ? 0.0f : m;                                        \
        }                                                                \
    }

__global__ __launch_bounds__(64, 1)
void lif_kernel(const float* __restrict__ x, float* __restrict__ out) {
    const int bid  = blockIdx.x;
    const int lane = threadIdx.x;

    if (bid >= NCOMPUTE) {
        // ---- prefetch role: stream x to warm L3, results unused ----
        const int p   = bid - NCOMPUTE;
        const int per = (UNITS + NPREFETCH - 1) / NPREFETCH;   // 86
        const char* __restrict__ xc = reinterpret_cast<const char*>(x);
        float acc = 0.0f;
        for (int i = 0; i < per; ++i) {
            const int u = p * per + i;
            if (u < UNITS) {
                const f32x4 v = *reinterpret_cast<const f32x4*>(
                    xc + (size_t)u * 1024 + (size_t)lane * 16);
                acc += v.x + v.y + v.z + v.w;   // uses all 4 -> full dwordx4 kept
            }
        }
        asm volatile("" ::"v"(acc));            // keep loads alive (no DCE)
        return;
    }

    // ---- compute role: exact sequential LIF, 1 chain per lane ----
    const int tid = bid * 64 + lane;            // 0..32767
    const int b = tid >> 9;                     // / FEAT
    const int f = tid & (FEAT - 1);
    const size_t base = (size_t)b * SEQ * FEAT + f;
    const float* __restrict__ xp = x + base;
    float* __restrict__ op = out + base;

    float m = 0.0f;
    float bufA[CHUNK], bufB[CHUNK];

    LOAD_CHUNK(bufA, 0)

    // 1024 / (2*64) = 8 iterations; static ping-pong, no register-copy join
    for (int t0 = 0; t0 < SEQ; t0 += 2 * CHUNK) {
        LOAD_CHUNK(bufB, t0 + CHUNK)          // prefetch while computing A
        COMPUTE_CHUNK(bufA, t0)
        if (t0 + 2 * CHUNK < SEQ) {
            LOAD_CHUNK(bufA, t0 + 2 * CHUNK)  // prefetch while computing B
        }
        COMPUTE_CHUNK(bufB, t0 + CHUNK)
    }
}

extern "C" void kernel_launch(void* const* d_in, const int* in_sizes, int n_in,
                              void* d_out, int out_size, void* d_ws, size_t ws_size,
                              hipStream_t stream) {
    const float* x = (const float*)d_in[0];
    float* out = (float*)d_out;
    const int grid = NCOMPUTE + NPREFETCH;      // 2048 blocks, ~8/CU
    lif_kernel<<<grid, 64, 0, stream>>>(x, out);
}

// Round 7
// 53.119 us; speedup vs baseline: 1.2018x; 1.2018x over previous
//
#include <hip/hip_runtime.h>

// LIF neuron scan: x [64, 1024, 512] f32 -> spikes [64, 1024, 512] f32 (0/1)
// m = 0.95*m + x[t]; s = (m > 0.5); m = s ? 0 : m
// 32768 sequential chains -> 512 single-wave blocks (2/CU).
//
// Round-6 falsified the "thin request stream" theory (4x read waves -> 36%
// SLOWER). Steady-state graph replays fetch only 65MB of x because half of x
// stays L3-resident; the other half is evicted by the 128MB output stream,
// which allocates in L3 despite the nt bit (observed 50/50 split of the
// 256MB Infinity Cache). This round: system-scope non-temporal stores
// (global_store_dword ... sc0 sc1 nt) to push the write stream past L3, so
// x (128MB) becomes FULLY L3-resident across replays -> steady-state HBM
// traffic drops from ~196MB to ~131MB (writes only), reads come at L3 BW.
//
// Compute structure = round-3 best (46.9us): CHUNK=64 static ping-pong
// register double-buffer, ~64 outstanding loads/wave. Non-fused mul/add
// (np ref rounds separately; the 0/1 threshold makes ulp differences
// avalanche down the chain) -> absmax stays 0.
// Stores use the saddr form (wave-uniform SGPR base + 32-bit voffset):
// 1 VALU addr op per store instead of a 64-bit pair add.

#define BATCH 64
#define SEQ   1024
#define FEAT  512
#define CHUNK 64

#define LOAD_CHUNK(buf, t0)                                              \
    {                                                                    \
        const float* __restrict__ xn = xp + (size_t)(t0) * FEAT;         \
        _Pragma("unroll")                                                \
        for (int u = 0; u < CHUNK; ++u) buf[u] = xn[(size_t)u * FEAT];   \
    }

// system-scope nt store: bypass L2/L3 allocation for the write-once output
#define COMPUTE_CHUNK(buf, t0)                                           \
    {                                                                    \
        _Pragma("unroll")                                                \
        for (int u = 0; u < CHUNK; ++u) {                                \
            m = __fadd_rn(__fmul_rn(0.95f, m), buf[u]);                  \
            const bool fired = (m > 0.5f);                               \
            const float sval = fired ? 1.0f : 0.0f;                      \
            const unsigned voff =                                        \
                lane4 + (unsigned)(((t0) + u) * (FEAT * 4));             \
            asm volatile("global_store_dword %0, %1, %2 sc0 sc1 nt"      \
                         :: "v"(voff), "v"(sval), "s"(obase));           \
            m = fired ? 0.0f : m;                                        \
        }                                                                \
    }

__global__ __launch_bounds__(64, 1)
void lif_kernel(const float* __restrict__ x, float* __restrict__ out) {
    const int bid  = blockIdx.x;
    const int lane = threadIdx.x;
    const int b    = bid >> 3;            // batch row   (8 blocks per row)
    const int f0   = (bid & 7) << 6;      // 64-feature group

    const float* __restrict__ xp = x + (size_t)b * SEQ * FEAT + f0 + lane;
    float* obase = out + (size_t)b * SEQ * FEAT + f0;   // wave-uniform base
    const unsigned lane4 = (unsigned)lane * 4u;

    float m = 0.0f;
    float bufA[CHUNK], bufB[CHUNK];

    LOAD_CHUNK(bufA, 0)

    // 1024 / (2*64) = 8 iterations; static ping-pong, no register-copy join
    for (int t0 = 0; t0 < SEQ; t0 += 2 * CHUNK) {
        LOAD_CHUNK(bufB, t0 + CHUNK)          // prefetch while computing A
        COMPUTE_CHUNK(bufA, t0)
        if (t0 + 2 * CHUNK < SEQ) {
            LOAD_CHUNK(bufA, t0 + 2 * CHUNK)  // prefetch while computing B
        }
        COMPUTE_CHUNK(bufB, t0 + CHUNK)
    }
}

extern "C" void kernel_launch(void* const* d_in, const int* in_sizes, int n_in,
                              void* d_out, int out_size, void* d_ws, size_t ws_size,
                              hipStream_t stream) {
    const float* x = (const float*)d_in[0];
    float* out = (float*)d_out;
    const int grid = BATCH * 8;              // 512 single-wave blocks
    lif_kernel<<<grid, 64, 0, stream>>>(x, out);
}